// Round 4
// baseline (281.586 us; speedup 1.0000x reference)
//
#include <hip/hip_runtime.h>

#define V 5003
#define BB 64
#define SS 200
#define DD 128
#define TAU 0.07f
#define LOG2E 1.4426950408889634f
#define LN2 0.6931471805599453f
#define SHIFT 8.0f   // lse = SHIFT + log(sum exp(x - SHIFT)); exact, overflow-proof for |x|<80

// ws layout (floats):
//   [0      .. 16384)  per-row float2 {focal_partial, valid}   (8192 rows)
//   [16384  .. 16448)  contrastive loss per batch
//   [16448  .. 16512)  contrastive n_anch per batch (as float)
#define WS_CS 16384
#define WS_PR 16448

__global__ __launch_bounds__(256) void fused_loss_kernel(
    const float* __restrict__ logits,   // [64,128,5003]
    const int*   __restrict__ targets,  // [64,128]
    const int*   __restrict__ mmask,    // [64,128]
    const float* __restrict__ emb,      // [64,200,128]
    const int*   __restrict__ pids,     // [64,200]
    const int*   __restrict__ amask,    // [64,200]
    float* __restrict__ ws)
{
    const int tid  = threadIdx.x;
    const int lane = tid & 63;
    const int wave = tid >> 6;

    __shared__ float wsum[4];
    __shared__ __align__(16) float anchors[8][DD];
    __shared__ float possim[8];
    __shared__ unsigned char validb[SS];
    __shared__ short poslist[16];
    __shared__ int   n_sh;
    __shared__ int   nanch_sh;
    __shared__ float red[4][8];
    __shared__ float contrib_sh[8];

    if (blockIdx.x < 8192) {
        // ========== FOCAL: one block per row, all loads issued up-front ==========
        const int r = blockIdx.x;
        const float* row = logits + (size_t)r * V;

        // block-uniform scalar loads (s_load path) — latency hidden under bulk
        const int tg = targets[r];
        const int mk = mmask[r];
        const int tc = tg < 0 ? 0 : tg;
        const float xt = row[tc];

        // alignment peel: row start element = r*5003; start%4 == (3r)%4
        const int p = (4 - ((r * 3) & 3)) & 3;   // head scalars
        const int t = 3 - p;                     // tail scalars; always 1250 aligned float4
        const float4* row4 = (const float4*)(row + p);
        const float C = -SHIFT * LOG2E;

        // ---- issue everything before consuming anything ----
        float4 v0 = row4[tid];
        float4 v1 = row4[tid + 256];
        float4 v2 = row4[tid + 512];
        float4 v3 = row4[tid + 768];
        const int  i4 = tid + 1024;
        const bool ok = i4 < 1250;               // tid < 226
        float4 v4 = row4[ok ? i4 : 0];
        float h = (tid < p) ? row[tid] : -1e30f;
        float u = (tid < t) ? row[p + 5000 + tid] : -1e30f;
        if (!ok) { v4.x = -1e30f; v4.y = -1e30f; v4.z = -1e30f; v4.w = -1e30f; }

        float s0 = exp2f(fmaf(v0.x, LOG2E, C)) + exp2f(fmaf(v1.x, LOG2E, C))
                 + exp2f(fmaf(v2.x, LOG2E, C)) + exp2f(fmaf(v3.x, LOG2E, C))
                 + exp2f(fmaf(v4.x, LOG2E, C));
        float s1 = exp2f(fmaf(v0.y, LOG2E, C)) + exp2f(fmaf(v1.y, LOG2E, C))
                 + exp2f(fmaf(v2.y, LOG2E, C)) + exp2f(fmaf(v3.y, LOG2E, C))
                 + exp2f(fmaf(v4.y, LOG2E, C));
        float s2 = exp2f(fmaf(v0.z, LOG2E, C)) + exp2f(fmaf(v1.z, LOG2E, C))
                 + exp2f(fmaf(v2.z, LOG2E, C)) + exp2f(fmaf(v3.z, LOG2E, C))
                 + exp2f(fmaf(v4.z, LOG2E, C));
        float s3 = exp2f(fmaf(v0.w, LOG2E, C)) + exp2f(fmaf(v1.w, LOG2E, C))
                 + exp2f(fmaf(v2.w, LOG2E, C)) + exp2f(fmaf(v3.w, LOG2E, C))
                 + exp2f(fmaf(v4.w, LOG2E, C));
        s0 += exp2f(fmaf(h, LOG2E, C)) + exp2f(fmaf(u, LOG2E, C));

        float s = (s0 + s1) + (s2 + s3);
        for (int off = 32; off; off >>= 1)
            s += __shfl_xor(s, off, 64);
        if (lane == 0) wsum[wave] = s;
        __syncthreads();

        if (tid == 0) {
            float S = (wsum[0] + wsum[1]) + (wsum[2] + wsum[3]);
            bool valid = (tg != -100) && (mk == 1);
            float lse = SHIFT + log2f(S) * LN2;
            float lp  = xt - lse;                // log p_t
            float pt  = exp2f(lp * LOG2E);
            float om  = 1.0f - pt;
            float fs  = valid ? (om * om * (-lp)) : 0.0f;
            ((float2*)ws)[r] = make_float2(fs, valid ? 1.0f : 0.0f);
        }
    } else {
        // ================= CONTRASTIVE: one block per batch =================
        const int b = blockIdx.x - 8192;

        if (tid == 0) n_sh = 0;
        __syncthreads();

        if (tid < SS) {
            int idx = b * SS + tid;
            bool v = (amask[idx] == 1) && (pids[idx] > 0);
            validb[tid] = v ? 1 : 0;
            if (v) atomicAdd(&n_sh, 1);          // LDS atomic — block-local
        }
        __syncthreads();

        if (tid == 0) {
            int cnt = 0;
            for (int s = 0; s < SS && cnt < 16; ++s)
                if (validb[s]) poslist[cnt++] = (short)s;
            for (; cnt < 16; ++cnt) poslist[cnt] = (short)(SS - 1);
            int n  = n_sh;
            int na = n / 2;
            if (na > 8) na = 8;
            nanch_sh = na;
        }
        __syncthreads();
        const int n_anch = nanch_sh;

        const float2* embb = (const float2*)(emb + (size_t)b * SS * DD);
        for (int jj = 0; jj < 2; ++jj) {
            int j = wave + jj * 4;
            if (j < n_anch) {
                int ai = poslist[j];
                int pi = poslist[n_anch + j];
                float2 a2 = embb[ai * 64 + lane];
                float2 p2 = embb[pi * 64 + lane];
                float na_ = a2.x * a2.x + a2.y * a2.y;
                float np_ = p2.x * p2.x + p2.y * p2.y;
                float dp  = a2.x * p2.x + a2.y * p2.y;
                for (int off = 32; off; off >>= 1) {
                    na_ += __shfl_xor(na_, off, 64);
                    np_ += __shfl_xor(np_, off, 64);
                    dp  += __shfl_xor(dp,  off, 64);
                }
                float rna = 1.0f / fmaxf(sqrtf(na_), 1e-12f);
                float rnp = 1.0f / fmaxf(sqrtf(np_), 1e-12f);
                anchors[j][2 * lane]     = a2.x * rna;
                anchors[j][2 * lane + 1] = a2.y * rna;
                if (lane == 0) possim[j] = dp * rna * rnp * (1.0f / TAU);
            } else {
                anchors[j][2 * lane]     = 0.0f;
                anchors[j][2 * lane + 1] = 0.0f;
                if (lane == 0) possim[j] = 0.0f;
            }
        }
        __syncthreads();

        float part[8];
        #pragma unroll
        for (int j = 0; j < 8; ++j) part[j] = 0.0f;

        for (int i = 0; i < 4; ++i) {
            int g = tid + i * 256;
            if (g < 4 * SS) {
                int ol = g / SS;
                int s  = g - ol * SS;
                int o  = (ol >= b) ? ol + 1 : ol;
                int idx = o * SS + s;
                if (amask[idx] == 1 && pids[idx] > 0) {
                    const float4* nb = (const float4*)(emb + (size_t)idx * DD);
                    float acc[8];
                    float n2 = 0.0f;
                    #pragma unroll
                    for (int j = 0; j < 8; ++j) acc[j] = 0.0f;
                    #pragma unroll 8
                    for (int c = 0; c < DD / 4; ++c) {
                        float4 x = nb[c];
                        n2 += x.x * x.x + x.y * x.y + x.z * x.z + x.w * x.w;
                        #pragma unroll
                        for (int j = 0; j < 8; ++j) {
                            float4 a = ((const float4*)anchors[j])[c];
                            acc[j] += a.x * x.x + a.y * x.y + a.z * x.z + a.w * x.w;
                        }
                    }
                    float rn = 1.0f / fmaxf(sqrtf(n2), 1e-12f);
                    #pragma unroll
                    for (int j = 0; j < 8; ++j) {
                        float sim = acc[j] * rn * (1.0f / TAU);
                        part[j] += exp2f(sim * LOG2E);   // |sim|<=14.3: safe
                    }
                }
            }
        }

        #pragma unroll
        for (int j = 0; j < 8; ++j)
            for (int off = 32; off; off >>= 1)
                part[j] += __shfl_xor(part[j], off, 64);
        if (lane == 0) {
            #pragma unroll
            for (int j = 0; j < 8; ++j) red[wave][j] = part[j];
        }
        __syncthreads();

        if (tid < 8) {
            int j = tid;
            float ps = possim[j];
            float S  = exp2f(ps * LOG2E) + red[0][j] + red[1][j] + red[2][j] + red[3][j];
            float lse = log2f(S) * LN2;
            contrib_sh[j] = (j < n_anch) ? (lse - ps) : 0.0f;
        }
        __syncthreads();
        if (tid == 0) {
            float lb = 0.0f;
            for (int j = 0; j < 8; ++j) lb += contrib_sh[j];
            ws[WS_CS + b] = lb;
            ws[WS_PR + b] = (float)n_anch;
        }
    }
}

__global__ __launch_bounds__(1024) void finalize_kernel(
    const float* __restrict__ ws, float* __restrict__ out)
{
    const int tid  = threadIdx.x;
    const int lane = tid & 63;
    const int wave = tid >> 6;
    __shared__ float r_fs[16], r_vc[16], r_cs[16], r_pr[16];

    const float2* f2 = (const float2*)ws;
    float fs = 0.f, vc = 0.f, cs = 0.f, pr = 0.f;
    #pragma unroll
    for (int i = 0; i < 8; ++i) {
        float2 v = f2[tid + i * 1024];
        fs += v.x; vc += v.y;
    }
    if (tid < 64) {
        cs = ws[WS_CS + tid];
        pr = ws[WS_PR + tid];
    }
    for (int off = 32; off; off >>= 1) {
        fs += __shfl_xor(fs, off, 64);
        vc += __shfl_xor(vc, off, 64);
        cs += __shfl_xor(cs, off, 64);
        pr += __shfl_xor(pr, off, 64);
    }
    if (lane == 0) { r_fs[wave] = fs; r_vc[wave] = vc; r_cs[wave] = cs; r_pr[wave] = pr; }
    __syncthreads();
    if (tid == 0) {
        float FS = 0.f, VC = 0.f;
        for (int w = 0; w < 16; ++w) { FS += r_fs[w]; VC += r_vc[w]; }
        float CS = r_cs[0], PR = r_pr[0];   // contrastive lived in wave 0 only
        float focal = VC > 0.0f ? FS / VC : 0.0f;
        float contr = PR > 0.0f ? CS / PR : 0.0f;
        out[0] = 0.6f * focal + 0.2f * contr;
    }
}

extern "C" void kernel_launch(void* const* d_in, const int* in_sizes, int n_in,
                              void* d_out, int out_size, void* d_ws, size_t ws_size,
                              hipStream_t stream) {
    const float* logits  = (const float*)d_in[0];
    const int*   targets = (const int*)d_in[1];
    const int*   mmask   = (const int*)d_in[2];
    const float* emb     = (const float*)d_in[3];
    const int*   pids    = (const int*)d_in[4];
    const int*   amask   = (const int*)d_in[5];
    float* out = (float*)d_out;
    float* ws  = (float*)d_ws;

    hipLaunchKernelGGL(fused_loss_kernel, dim3(8192 + 64), dim3(256), 0, stream,
                       logits, targets, mmask, emb, pids, amask, ws);
    hipLaunchKernelGGL(finalize_kernel, dim3(1), dim3(1024), 0, stream, ws, out);
}

// Round 5
// 278.836 us; speedup vs baseline: 1.0099x; 1.0099x over previous
//
#include <hip/hip_runtime.h>

#define V 5003
#define SS 200
#define DD 128
#define TAU 0.07f
#define LOG2E 1.4426950408889634f
#define LN2 0.6931471805599453f
#define SHIFT 8.0f   // lse = SHIFT + log(sum exp(x-SHIFT)); exact, overflow-proof for |x|<80

// ws layout (floats):
//   [0      .. 16384)  per-row float2 {focal_partial, valid}   (8192 rows)
//   [16384  .. 16448)  contrastive loss per batch
//   [16448  .. 16512)  contrastive n_anch per batch (as float)
#define WS_CS 16384
#define WS_PR 16448

#define NFB 1024   // focal blocks; 4096 focal waves, 2 rows per wave

__global__ __launch_bounds__(256) void fused_loss_kernel(
    const float* __restrict__ logits,   // [64,128,5003]
    const int*   __restrict__ targets,  // [64,128]
    const int*   __restrict__ mmask,    // [64,128]
    const float* __restrict__ emb,      // [64,200,128]
    const int*   __restrict__ pids,     // [64,200]
    const int*   __restrict__ amask,    // [64,200]
    float* __restrict__ ws)
{
    const int tid  = threadIdx.x;
    const int lane = tid & 63;
    const int wave = tid >> 6;

    __shared__ __align__(16) float anchors[8][DD];
    __shared__ float possim[8];
    __shared__ unsigned char validb[SS];
    __shared__ short poslist[16];
    __shared__ int   n_sh;
    __shared__ int   nanch_sh;
    __shared__ float red[4][8];
    __shared__ float contrib_sh[8];

    if (blockIdx.x < NFB) {
        // ===== FOCAL: one wave per row-pair, 40-step pipelined stream =====
        const int W  = blockIdx.x * 4 + wave;   // 0..4095
        const int r0 = W;
        const int r1 = W + 4096;
        const float* rowp0 = logits + (size_t)r0 * V;
        const float* rowp1 = logits + (size_t)r1 * V;

        // row start alignment: start%4 == (3*r)%4; r1=r0+4096 -> same p
        const int p = (4 - ((r0 * 3) & 3)) & 3;
        const int t = 3 - p;
        const float4* b0 = (const float4*)(rowp0 + p);
        const float4* b1 = (const float4*)(rowp1 + p);
        const float C = -SHIFT * LOG2E;

        // uniform-ish loads issued early (latency hidden under the stream)
        const int tg0 = targets[r0], tg1 = targets[r1];
        const int mk0 = mmask[r0],  mk1 = mmask[r1];

        // head/tail scalars (predicated) — issued in prologue, consumed at end
        float h0 = (lane < p) ? rowp0[lane] : -1e30f;
        float u0 = (lane < t) ? rowp0[p + 5000 + lane] : -1e30f;
        float h1 = (lane < p) ? rowp1[lane] : -1e30f;
        float u1 = (lane < t) ? rowp1[p + 5000 + lane] : -1e30f;

        // pipeline prologue: steps 0..3 (all row0, full steps)
        float4 buf[4];
        #pragma unroll
        for (int k = 0; k < 4; ++k)
            buf[k] = b0[k * 64 + lane];

        // target logits (dependent on tg loads; bulk already in flight)
        const float xt0 = rowp0[tg0 < 0 ? 0 : tg0];
        const float xt1 = rowp1[tg1 < 0 ? 0 : tg1];

        const int l19 = (lane < 34) ? lane : 0;  // clamped lane for partial step

        float sa0=0.f,sa1=0.f,sa2=0.f,sa3=0.f;
        float sb0=0.f,sb1=0.f,sb2=0.f,sb3=0.f;

        // 40 flat steps (2 rows x 20), depth-4 rotating buffer:
        // issue load for step k+4, then consume step k. vmcnt never drains.
        #pragma unroll
        for (int k = 0; k < 40; ++k) {
            float4 nxt;
            if (k + 4 < 40) {
                const int  kk = k + 4;
                const bool A  = kk < 20;
                const int  j  = A ? kk : kk - 20;
                const float4* base = A ? b0 : b1;
                const int idx = (j < 19) ? (j * 64 + lane) : (1216 + l19);
                nxt = base[idx];
            } else {
                nxt = make_float4(-1e30f, -1e30f, -1e30f, -1e30f);
            }
            float4 x = buf[k & 3];
            const int j = (k < 20) ? k : k - 20;
            if (j == 19 && lane >= 34) { x.x = -1e30f; x.y = -1e30f; x.z = -1e30f; x.w = -1e30f; }
            float e0 = exp2f(fmaf(x.x, LOG2E, C));
            float e1 = exp2f(fmaf(x.y, LOG2E, C));
            float e2 = exp2f(fmaf(x.z, LOG2E, C));
            float e3 = exp2f(fmaf(x.w, LOG2E, C));
            if (k < 20) { sa0 += e0; sa1 += e1; sa2 += e2; sa3 += e3; }
            else        { sb0 += e0; sb1 += e1; sb2 += e2; sb3 += e3; }
            buf[k & 3] = nxt;
        }
        sa0 += exp2f(fmaf(h0, LOG2E, C)) + exp2f(fmaf(u0, LOG2E, C));
        sb0 += exp2f(fmaf(h1, LOG2E, C)) + exp2f(fmaf(u1, LOG2E, C));

        float sA = (sa0 + sa1) + (sa2 + sa3);
        float sB = (sb0 + sb1) + (sb2 + sb3);
        for (int off = 32; off; off >>= 1) {
            sA += __shfl_xor(sA, off, 64);
            sB += __shfl_xor(sB, off, 64);
        }
        if (lane == 0) {
            {
                bool valid = (tg0 != -100) && (mk0 == 1);
                float lse = SHIFT + log2f(sA) * LN2;
                float lp  = xt0 - lse;
                float pt  = exp2f(lp * LOG2E);
                float om  = 1.0f - pt;
                ((float2*)ws)[r0] = make_float2(valid ? (om * om * (-lp)) : 0.0f,
                                                valid ? 1.0f : 0.0f);
            }
            {
                bool valid = (tg1 != -100) && (mk1 == 1);
                float lse = SHIFT + log2f(sB) * LN2;
                float lp  = xt1 - lse;
                float pt  = exp2f(lp * LOG2E);
                float om  = 1.0f - pt;
                ((float2*)ws)[r1] = make_float2(valid ? (om * om * (-lp)) : 0.0f,
                                                valid ? 1.0f : 0.0f);
            }
        }
    } else {
        // ================= CONTRASTIVE: one block per batch =================
        const int b = blockIdx.x - NFB;

        if (tid == 0) n_sh = 0;
        __syncthreads();

        if (tid < SS) {
            int idx = b * SS + tid;
            bool v = (amask[idx] == 1) && (pids[idx] > 0);
            validb[tid] = v ? 1 : 0;
            if (v) atomicAdd(&n_sh, 1);          // LDS atomic — block-local
        }
        __syncthreads();

        if (tid == 0) {
            int cnt = 0;
            for (int s = 0; s < SS && cnt < 16; ++s)
                if (validb[s]) poslist[cnt++] = (short)s;
            for (; cnt < 16; ++cnt) poslist[cnt] = (short)(SS - 1);
            int n  = n_sh;
            int na = n / 2;
            if (na > 8) na = 8;
            nanch_sh = na;
        }
        __syncthreads();
        const int n_anch = nanch_sh;

        const float2* embb = (const float2*)(emb + (size_t)b * SS * DD);
        for (int jj = 0; jj < 2; ++jj) {
            int j = wave + jj * 4;
            if (j < n_anch) {
                int ai = poslist[j];
                int pi = poslist[n_anch + j];
                float2 a2 = embb[ai * 64 + lane];
                float2 p2 = embb[pi * 64 + lane];
                float na_ = a2.x * a2.x + a2.y * a2.y;
                float np_ = p2.x * p2.x + p2.y * p2.y;
                float dp  = a2.x * p2.x + a2.y * p2.y;
                for (int off = 32; off; off >>= 1) {
                    na_ += __shfl_xor(na_, off, 64);
                    np_ += __shfl_xor(np_, off, 64);
                    dp  += __shfl_xor(dp,  off, 64);
                }
                float rna = 1.0f / fmaxf(sqrtf(na_), 1e-12f);
                float rnp = 1.0f / fmaxf(sqrtf(np_), 1e-12f);
                anchors[j][2 * lane]     = a2.x * rna;
                anchors[j][2 * lane + 1] = a2.y * rna;
                if (lane == 0) possim[j] = dp * rna * rnp * (1.0f / TAU);
            } else {
                anchors[j][2 * lane]     = 0.0f;
                anchors[j][2 * lane + 1] = 0.0f;
                if (lane == 0) possim[j] = 0.0f;
            }
        }
        __syncthreads();

        float part[8];
        #pragma unroll
        for (int j = 0; j < 8; ++j) part[j] = 0.0f;

        for (int i = 0; i < 4; ++i) {
            int g = tid + i * 256;
            if (g < 4 * SS) {
                int ol = g / SS;
                int s  = g - ol * SS;
                int o  = (ol >= b) ? ol + 1 : ol;
                int idx = o * SS + s;
                if (amask[idx] == 1 && pids[idx] > 0) {
                    const float4* nb = (const float4*)(emb + (size_t)idx * DD);
                    float acc[8];
                    float n2 = 0.0f;
                    #pragma unroll
                    for (int j = 0; j < 8; ++j) acc[j] = 0.0f;
                    #pragma unroll 8
                    for (int c = 0; c < DD / 4; ++c) {
                        float4 x = nb[c];
                        n2 += x.x * x.x + x.y * x.y + x.z * x.z + x.w * x.w;
                        #pragma unroll
                        for (int j = 0; j < 8; ++j) {
                            float4 a = ((const float4*)anchors[j])[c];
                            acc[j] += a.x * x.x + a.y * x.y + a.z * x.z + a.w * x.w;
                        }
                    }
                    float rn = 1.0f / fmaxf(sqrtf(n2), 1e-12f);
                    #pragma unroll
                    for (int j = 0; j < 8; ++j) {
                        float sim = acc[j] * rn * (1.0f / TAU);
                        part[j] += exp2f(sim * LOG2E);   // |sim|<=14.3: safe
                    }
                }
            }
        }

        #pragma unroll
        for (int j = 0; j < 8; ++j)
            for (int off = 32; off; off >>= 1)
                part[j] += __shfl_xor(part[j], off, 64);
        if (lane == 0) {
            #pragma unroll
            for (int j = 0; j < 8; ++j) red[wave][j] = part[j];
        }
        __syncthreads();

        if (tid < 8) {
            int j = tid;
            float ps = possim[j];
            float S  = exp2f(ps * LOG2E) + red[0][j] + red[1][j] + red[2][j] + red[3][j];
            float lse = log2f(S) * LN2;
            contrib_sh[j] = (j < n_anch) ? (lse - ps) : 0.0f;
        }
        __syncthreads();
        if (tid == 0) {
            float lb = 0.0f;
            for (int j = 0; j < 8; ++j) lb += contrib_sh[j];
            ws[WS_CS + b] = lb;
            ws[WS_PR + b] = (float)n_anch;
        }
    }
}

__global__ __launch_bounds__(1024) void finalize_kernel(
    const float* __restrict__ ws, float* __restrict__ out)
{
    const int tid  = threadIdx.x;
    const int lane = tid & 63;
    const int wave = tid >> 6;
    __shared__ float r_fs[16], r_vc[16], r_cs[16], r_pr[16];

    const float2* f2 = (const float2*)ws;
    float fs = 0.f, vc = 0.f, cs = 0.f, pr = 0.f;
    #pragma unroll
    for (int i = 0; i < 8; ++i) {
        float2 v = f2[tid + i * 1024];
        fs += v.x; vc += v.y;
    }
    if (tid < 64) {
        cs = ws[WS_CS + tid];
        pr = ws[WS_PR + tid];
    }
    for (int off = 32; off; off >>= 1) {
        fs += __shfl_xor(fs, off, 64);
        vc += __shfl_xor(vc, off, 64);
        cs += __shfl_xor(cs, off, 64);
        pr += __shfl_xor(pr, off, 64);
    }
    if (lane == 0) { r_fs[wave] = fs; r_vc[wave] = vc; r_cs[wave] = cs; r_pr[wave] = pr; }
    __syncthreads();
    if (tid == 0) {
        float FS = 0.f, VC = 0.f;
        for (int w = 0; w < 16; ++w) { FS += r_fs[w]; VC += r_vc[w]; }
        float CS = r_cs[0], PR = r_pr[0];   // contrastive reduced in wave 0 only
        float focal = VC > 0.0f ? FS / VC : 0.0f;
        float contr = PR > 0.0f ? CS / PR : 0.0f;
        out[0] = 0.6f * focal + 0.2f * contr;
    }
}

extern "C" void kernel_launch(void* const* d_in, const int* in_sizes, int n_in,
                              void* d_out, int out_size, void* d_ws, size_t ws_size,
                              hipStream_t stream) {
    const float* logits  = (const float*)d_in[0];
    const int*   targets = (const int*)d_in[1];
    const int*   mmask   = (const int*)d_in[2];
    const float* emb     = (const float*)d_in[3];
    const int*   pids    = (const int*)d_in[4];
    const int*   amask   = (const int*)d_in[5];
    float* out = (float*)d_out;
    float* ws  = (float*)d_ws;

    hipLaunchKernelGGL(fused_loss_kernel, dim3(NFB + 64), dim3(256), 0, stream,
                       logits, targets, mmask, emb, pids, amask, ws);
    hipLaunchKernelGGL(finalize_kernel, dim3(1), dim3(1024), 0, stream, ws, out);
}

// Round 6
// 269.491 us; speedup vs baseline: 1.0449x; 1.0347x over previous
//
#include <hip/hip_runtime.h>

#define V 5003
#define SS 200
#define DD 128
#define TAU 0.07f
#define LOG2E 1.4426950408889634f
#define LN2 0.6931471805599453f
#define SHIFT 8.0f   // lse = SHIFT + log(sum exp(x-SHIFT)); exact, overflow-proof for |x|<80

// ws layout (floats):
//   [0      .. 16384)  per-row float2 {focal_partial, valid}   (8192 rows)
//   [16384  .. 16448)  contrastive loss per batch
//   [16448  .. 16512)  contrastive n_anch per batch (as float)
#define WS_CS 16384
#define WS_PR 16448

#define NFB 2048   // focal blocks; 8192 focal waves, 1 row per wave

typedef float f4 __attribute__((ext_vector_type(4)));

__device__ __forceinline__ f4 ldnt4(const f4* p) {
    return __builtin_nontemporal_load(p);      // nt: streaming / no-allocate hint
}
__device__ __forceinline__ float ldnt1(const float* p) {
    return __builtin_nontemporal_load(p);
}

__global__ __launch_bounds__(256) void fused_loss_kernel(
    const float* __restrict__ logits,   // [64,128,5003]
    const int*   __restrict__ targets,  // [64,128]
    const int*   __restrict__ mmask,    // [64,128]
    const float* __restrict__ emb,      // [64,200,128]
    const int*   __restrict__ pids,     // [64,200]
    const int*   __restrict__ amask,    // [64,200]
    float* __restrict__ ws)
{
    const int tid  = threadIdx.x;
    const int lane = tid & 63;
    const int wave = tid >> 6;

    __shared__ __align__(16) float anchors[8][DD];
    __shared__ float possim[8];
    __shared__ unsigned char validb[SS];
    __shared__ short poslist[16];
    __shared__ int   n_sh;
    __shared__ int   nanch_sh;
    __shared__ float red[4][8];
    __shared__ float contrib_sh[8];

    if (blockIdx.x < NFB) {
        // ===== FOCAL: one wave per row, depth-4 pipelined nontemporal stream =====
        const int r = blockIdx.x * 4 + wave;    // 0..8191
        const float* rowp = logits + (size_t)r * V;

        // row start alignment: start%4 == (3*r)%4
        const int p = (4 - ((r * 3) & 3)) & 3;
        const int t = 3 - p;
        const f4* b0 = (const f4*)(rowp + p);   // 1250 aligned float4
        const float C = -SHIFT * LOG2E;

        const int tg = targets[r];
        const int mk = mmask[r];

        // head/tail scalars (predicated), issued early
        float h = (lane < p) ? ldnt1(rowp + lane) : -1e30f;
        float u = (lane < t) ? ldnt1(rowp + p + 5000 + lane) : -1e30f;

        // pipeline prologue: steps 0..3
        f4 buf[4];
        #pragma unroll
        for (int k = 0; k < 4; ++k)
            buf[k] = ldnt4(b0 + k * 64 + lane);

        // target logit (uniform-ish; bulk already in flight). Regular load.
        const float xt = rowp[tg < 0 ? 0 : tg];

        const int l19 = (lane < 34) ? lane : 0;  // clamped lane for partial step

        float s0 = 0.f, s1 = 0.f, s2 = 0.f, s3 = 0.f;

        // 20 steps, depth-4 rotating buffer: issue k+4, consume k.
        #pragma unroll
        for (int k = 0; k < 20; ++k) {
            f4 nxt;
            if (k + 4 < 20) {
                const int kk  = k + 4;
                const int idx = (kk < 19) ? (kk * 64 + lane) : (1216 + l19);
                nxt = ldnt4(b0 + idx);
            } else {
                nxt = (f4)(-1e30f);
            }
            f4 x = buf[k & 3];
            if (k == 19 && lane >= 34) x = (f4)(-1e30f);
            s0 += exp2f(fmaf(x.x, LOG2E, C));
            s1 += exp2f(fmaf(x.y, LOG2E, C));
            s2 += exp2f(fmaf(x.z, LOG2E, C));
            s3 += exp2f(fmaf(x.w, LOG2E, C));
            buf[k & 3] = nxt;
        }
        s0 += exp2f(fmaf(h, LOG2E, C)) + exp2f(fmaf(u, LOG2E, C));

        float s = (s0 + s1) + (s2 + s3);
        for (int off = 32; off; off >>= 1)
            s += __shfl_xor(s, off, 64);

        if (lane == 0) {
            bool valid = (tg != -100) && (mk == 1);
            float lse = SHIFT + log2f(s) * LN2;
            float lp  = xt - lse;                // log p_t
            float pt  = exp2f(lp * LOG2E);
            float om  = 1.0f - pt;
            ((float2*)ws)[r] = make_float2(valid ? (om * om * (-lp)) : 0.0f,
                                           valid ? 1.0f : 0.0f);
        }
    } else {
        // ================= CONTRASTIVE: one block per batch =================
        const int b = blockIdx.x - NFB;

        if (tid == 0) n_sh = 0;
        __syncthreads();

        if (tid < SS) {
            int idx = b * SS + tid;
            bool v = (amask[idx] == 1) && (pids[idx] > 0);
            validb[tid] = v ? 1 : 0;
            if (v) atomicAdd(&n_sh, 1);          // LDS atomic — block-local
        }
        __syncthreads();

        if (tid == 0) {
            int cnt = 0;
            for (int s = 0; s < SS && cnt < 16; ++s)
                if (validb[s]) poslist[cnt++] = (short)s;
            for (; cnt < 16; ++cnt) poslist[cnt] = (short)(SS - 1);
            int n  = n_sh;
            int na = n / 2;
            if (na > 8) na = 8;
            nanch_sh = na;
        }
        __syncthreads();
        const int n_anch = nanch_sh;

        const float2* embb = (const float2*)(emb + (size_t)b * SS * DD);
        for (int jj = 0; jj < 2; ++jj) {
            int j = wave + jj * 4;
            if (j < n_anch) {
                int ai = poslist[j];
                int pi = poslist[n_anch + j];
                float2 a2 = embb[ai * 64 + lane];
                float2 p2 = embb[pi * 64 + lane];
                float na_ = a2.x * a2.x + a2.y * a2.y;
                float np_ = p2.x * p2.x + p2.y * p2.y;
                float dp  = a2.x * p2.x + a2.y * p2.y;
                for (int off = 32; off; off >>= 1) {
                    na_ += __shfl_xor(na_, off, 64);
                    np_ += __shfl_xor(np_, off, 64);
                    dp  += __shfl_xor(dp,  off, 64);
                }
                float rna = 1.0f / fmaxf(sqrtf(na_), 1e-12f);
                float rnp = 1.0f / fmaxf(sqrtf(np_), 1e-12f);
                anchors[j][2 * lane]     = a2.x * rna;
                anchors[j][2 * lane + 1] = a2.y * rna;
                if (lane == 0) possim[j] = dp * rna * rnp * (1.0f / TAU);
            } else {
                anchors[j][2 * lane]     = 0.0f;
                anchors[j][2 * lane + 1] = 0.0f;
                if (lane == 0) possim[j] = 0.0f;
            }
        }
        __syncthreads();

        float part[8];
        #pragma unroll
        for (int j = 0; j < 8; ++j) part[j] = 0.0f;

        for (int i = 0; i < 4; ++i) {
            int g = tid + i * 256;
            if (g < 4 * SS) {
                int ol = g / SS;
                int s  = g - ol * SS;
                int o  = (ol >= b) ? ol + 1 : ol;
                int idx = o * SS + s;
                if (amask[idx] == 1 && pids[idx] > 0) {
                    const float4* nb = (const float4*)(emb + (size_t)idx * DD);
                    float acc[8];
                    float n2 = 0.0f;
                    #pragma unroll
                    for (int j = 0; j < 8; ++j) acc[j] = 0.0f;
                    #pragma unroll 8
                    for (int c = 0; c < DD / 4; ++c) {
                        float4 x = nb[c];
                        n2 += x.x * x.x + x.y * x.y + x.z * x.z + x.w * x.w;
                        #pragma unroll
                        for (int j = 0; j < 8; ++j) {
                            float4 a = ((const float4*)anchors[j])[c];
                            acc[j] += a.x * x.x + a.y * x.y + a.z * x.z + a.w * x.w;
                        }
                    }
                    float rn = 1.0f / fmaxf(sqrtf(n2), 1e-12f);
                    #pragma unroll
                    for (int j = 0; j < 8; ++j) {
                        float sim = acc[j] * rn * (1.0f / TAU);
                        part[j] += exp2f(sim * LOG2E);   // |sim|<=14.3: safe
                    }
                }
            }
        }

        #pragma unroll
        for (int j = 0; j < 8; ++j)
            for (int off = 32; off; off >>= 1)
                part[j] += __shfl_xor(part[j], off, 64);
        if (lane == 0) {
            #pragma unroll
            for (int j = 0; j < 8; ++j) red[wave][j] = part[j];
        }
        __syncthreads();

        if (tid < 8) {
            int j = tid;
            float ps = possim[j];
            float S  = exp2f(ps * LOG2E) + red[0][j] + red[1][j] + red[2][j] + red[3][j];
            float lse = log2f(S) * LN2;
            contrib_sh[j] = (j < n_anch) ? (lse - ps) : 0.0f;
        }
        __syncthreads();
        if (tid == 0) {
            float lb = 0.0f;
            for (int j = 0; j < 8; ++j) lb += contrib_sh[j];
            ws[WS_CS + b] = lb;
            ws[WS_PR + b] = (float)n_anch;
        }
    }
}

__global__ __launch_bounds__(1024) void finalize_kernel(
    const float* __restrict__ ws, float* __restrict__ out)
{
    const int tid  = threadIdx.x;
    const int lane = tid & 63;
    const int wave = tid >> 6;
    __shared__ float r_fs[16], r_vc[16], r_cs[16], r_pr[16];

    const float2* f2 = (const float2*)ws;
    float fs = 0.f, vc = 0.f, cs = 0.f, pr = 0.f;
    #pragma unroll
    for (int i = 0; i < 8; ++i) {
        float2 v = f2[tid + i * 1024];
        fs += v.x; vc += v.y;
    }
    if (tid < 64) {
        cs = ws[WS_CS + tid];
        pr = ws[WS_PR + tid];
    }
    for (int off = 32; off; off >>= 1) {
        fs += __shfl_xor(fs, off, 64);
        vc += __shfl_xor(vc, off, 64);
        cs += __shfl_xor(cs, off, 64);
        pr += __shfl_xor(pr, off, 64);
    }
    if (lane == 0) { r_fs[wave] = fs; r_vc[wave] = vc; r_cs[wave] = cs; r_pr[wave] = pr; }
    __syncthreads();
    if (tid == 0) {
        float FS = 0.f, VC = 0.f;
        for (int w = 0; w < 16; ++w) { FS += r_fs[w]; VC += r_vc[w]; }
        float CS = r_cs[0], PR = r_pr[0];   // contrastive reduced in wave 0 only
        float focal = VC > 0.0f ? FS / VC : 0.0f;
        float contr = PR > 0.0f ? CS / PR : 0.0f;
        out[0] = 0.6f * focal + 0.2f * contr;
    }
}

extern "C" void kernel_launch(void* const* d_in, const int* in_sizes, int n_in,
                              void* d_out, int out_size, void* d_ws, size_t ws_size,
                              hipStream_t stream) {
    const float* logits  = (const float*)d_in[0];
    const int*   targets = (const int*)d_in[1];
    const int*   mmask   = (const int*)d_in[2];
    const float* emb     = (const float*)d_in[3];
    const int*   pids    = (const int*)d_in[4];
    const int*   amask   = (const int*)d_in[5];
    float* out = (float*)d_out;
    float* ws  = (float*)d_ws;

    hipLaunchKernelGGL(fused_loss_kernel, dim3(NFB + 64), dim3(256), 0, stream,
                       logits, targets, mmask, emb, pids, amask, ws);
    hipLaunchKernelGGL(finalize_kernel, dim3(1), dim3(1024), 0, stream, ws, out);
}